// Round 12
// baseline (372.729 us; speedup 1.0000x reference)
//
#include <hip/hip_runtime.h>

#define OUT_H 256
#define OUT_W 192
#define NPIX  (OUT_H * OUT_W)   // 49152
#define NPP   (NPIX / 2)        // 24576 pixel-pairs
#define NB    256
#define NC    25                 // N_CTRL
#define NL    28                 // NC + 3
#define BCHUNK 8                 // batches per block (small: block turnover)

typedef float f4_t __attribute__((ext_vector_type(4)));

// ---------------------------------------------------------------------------
// Compile-time Li = inv(L) (first NC columns), fp64 Gauss-Jordan w/ partial
// pivoting, evaluated by the compiler. cx_log: ln via atanh series (~1e-16).
// ---------------------------------------------------------------------------
constexpr double cx_log(double x) {
    int k = 0;
    while (x > 1.5) { x *= 0.5; ++k; }
    while (x < 0.75) { x *= 2.0; --k; }
    double z = (x - 1.0) / (x + 1.0);
    double z2 = z * z;
    double t = z, s = 0.0;
    for (int i = 0; i < 16; ++i) { s += t / (double)(2 * i + 1); t *= z2; }
    return 2.0 * s + (double)k * 0.69314718055994530941723212145817656808;
}

struct LiMat { float v[NL][NC]; };

constexpr LiMat make_li() {
    double aug[NL][2 * NL] = {};
    const double ax[5] = {-1.0, -0.5, 0.0, 0.5, 1.0};
    for (int i = 0; i < NL; ++i)
        for (int j = 0; j < NL; ++j) {
            double v = 0.0;
            if (i < NC && j < NC) {
                double dx = ax[i / 5] - ax[j / 5];
                double dy = ax[i % 5] - ax[j % 5];
                double d2 = dx * dx + dy * dy;
                v = (d2 == 0.0) ? 0.0 : d2 * cx_log(d2);
            } else if (i < NC) {
                v = (j == NC) ? 1.0 : ((j == NC + 1) ? ax[i / 5] : ax[i % 5]);
            } else if (j < NC) {
                v = (i == NC) ? 1.0 : ((i == NC + 1) ? ax[j / 5] : ax[j % 5]);
            }
            aug[i][j] = (double)(float)v;   // mimic numpy's fp32 L build
        }
    for (int i = 0; i < NL; ++i) aug[i][NL + i] = 1.0;

    for (int k = 0; k < NL; ++k) {
        int p = k;
        double best = aug[k][k] < 0 ? -aug[k][k] : aug[k][k];
        for (int r = k + 1; r < NL; ++r) {
            double a = aug[r][k] < 0 ? -aug[r][k] : aug[r][k];
            if (a > best) { best = a; p = r; }
        }
        if (p != k)
            for (int j = k; j < 2 * NL; ++j) {
                double t = aug[k][j]; aug[k][j] = aug[p][j]; aug[p][j] = t;
            }
        const double ipv = 1.0 / aug[k][k];
        for (int j = k; j < 2 * NL; ++j) aug[k][j] *= ipv;
        for (int r = 0; r < NL; ++r) {
            if (r == k) continue;
            const double f = aug[r][k];
            if (f == 0.0) continue;
            for (int j = k; j < 2 * NL; ++j) aug[r][j] -= f * aug[k][j];
        }
    }
    LiMat o = {};
    for (int i = 0; i < NL; ++i)
        for (int j = 0; j < NC; ++j)
            o.v[i][j] = (float)aug[i][NL + j];
    return o;
}

constexpr LiMat LI_HOST = make_li();
__constant__ LiMat LI = LI_HOST;          // 2.8 KB, baked at compile time

// ---------------------------------------------------------------------------
// TLP/turnover build: grid (96, 32) = 3072 blocks of 256 thr, BCHUNK=8,
// PAIRS=1, coefficient halves read sequentially through ONE c[28] buffer.
// __launch_bounds__(256,5): cap VGPR ~102 -> 5 blocks/CU resident (20
// waves/CU vs R11's 12) + 2.4x block turnover to de-phase-lock the grid.
//  swc row layout (stride 56): [0..24]=WX [25..27]=AX | [28..52]=WY [53..55]=AY
// ---------------------------------------------------------------------------
__global__ __launch_bounds__(256, 5) void tps_fused(const float* __restrict__ theta,
                                                    f4_t* __restrict__ out4) {
    __shared__ float sth[BCHUNK * 2 * NC];   // 400 floats
    __shared__ float swc[BCHUNK][56];        // 8 x 56 coeffs

    const int tid = threadIdx.x;
    const int b0  = blockIdx.y * BCHUNK;

    // ---- stage theta slice (coalesced) ----
    {
        const int idx = tid;
        if (idx < BCHUNK * 2 * NC) sth[idx] = theta[b0 * 2 * NC + idx];
        if (idx + 256 < BCHUNK * 2 * NC) sth[idx + 256] = theta[b0 * 2 * NC + idx + 256];
    }
    __syncthreads();

    const float axf[5] = {-1.f, -0.5f, 0.f, 0.5f, 1.f};

    // ---- coefficients: 32 threads/batch, one Li row each (rows 0..27) ----
    {
        const int b = tid >> 5;          // batch 0..7
        const int r = tid & 31;          // row
        if (r < NL) {
            float sx = 0.f, sy = 0.f;
            #pragma unroll
            for (int m = 0; m < NC; ++m) {
                const float l  = LI.v[r][m];
                const float tx = sth[b * 2 * NC + m]      + axf[m / 5];
                const float ty = sth[b * 2 * NC + NC + m] + axf[m % 5];
                sx = fmaf(l, tx, sx);
                sy = fmaf(l, ty, sy);
            }
            swc[b][r]      = sx;         // rows 0..24 = WX, 25..27 = AX
            swc[b][28 + r] = sy;         // 28..52 = WY, 53..55 = AY
        }
    }

    // ---- per-thread radial basis for 1 pixel-pair (2 pixels) ----
    const int pp = blockIdx.x * 256 + tid;           // pixel-pair 0..24575
    const int h  = pp / (OUT_W / 2);
    const int w0 = (pp - h * (OUT_W / 2)) * 2;

    const float gy  = (h == OUT_H - 1) ? 1.f : (float)(-1.0 + h * (2.0 / (OUT_H - 1)));
    const float gx0 = (float)(-1.0 + w0 * (2.0 / (OUT_W - 1)));
    const float gx1 = (w0 + 1 == OUT_W - 1) ? 1.f
                                            : (float)(-1.0 + (w0 + 1) * (2.0 / (OUT_W - 1)));

    float U0[NC], U1[NC];
    #pragma unroll
    for (int n = 0; n < NC; ++n) {
        const float cx = axf[n / 5], cy = axf[n % 5];
        const float dy  = gy - cy;
        const float dx0 = gx0 - cx;
        const float d20 = dx0 * dx0 + dy * dy;
        U0[n] = (d20 == 0.f) ? 0.f : d20 * __logf(d20);
        const float dx1 = gx1 - cx;
        const float d21 = dx1 * dx1 + dy * dy;
        U1[n] = (d21 == 0.f) ? 0.f : d21 * __logf(d21);
    }

    __syncthreads();

    // ---- main loop over the block's 8 batches ----
    #pragma unroll 1
    for (int bi = 0; bi < BCHUNK; ++bi) {
        float c[28];
        // X half
        #pragma unroll
        for (int k = 0; k < 7; ++k)
            *(f4_t*)&c[k * 4] = *(const f4_t*)&swc[bi][k * 4];
        float X0 = fmaf(c[27], gy, fmaf(c[26], gx0, c[25]));
        float X1 = fmaf(c[27], gy, fmaf(c[26], gx1, c[25]));
        #pragma unroll
        for (int n = 0; n < NC; ++n) {
            X0 = fmaf(U0[n], c[n], X0);
            X1 = fmaf(U1[n], c[n], X1);
        }
        // Y half (reuse buffer)
        #pragma unroll
        for (int k = 0; k < 7; ++k)
            *(f4_t*)&c[k * 4] = *(const f4_t*)&swc[bi][28 + k * 4];
        float Y0 = fmaf(c[27], gy, fmaf(c[26], gx0, c[25]));
        float Y1 = fmaf(c[27], gy, fmaf(c[26], gx1, c[25]));
        #pragma unroll
        for (int n = 0; n < NC; ++n) {
            Y0 = fmaf(U0[n], c[n], Y0);
            Y1 = fmaf(U1[n], c[n], Y1);
        }
        f4_t v; v.x = X0; v.y = Y0; v.z = X1; v.w = Y1;
        __builtin_nontemporal_store(v, &out4[(size_t)(b0 + bi) * NPP + pp]);
    }
}

// ---------------------------------------------------------------------------
extern "C" void kernel_launch(void* const* d_in, const int* in_sizes, int n_in,
                              void* d_out, int out_size, void* d_ws, size_t ws_size,
                              hipStream_t stream) {
    const float* theta = (const float*)d_in[0];
    dim3 grid(NPP / 256, NB / BCHUNK);             // (96, 32) = 3072 blocks
    tps_fused<<<grid, 256, 0, stream>>>(theta, (f4_t*)d_out);
}

// Round 13
// 37.463 us; speedup vs baseline: 9.9491x; 9.9491x over previous
//
#include <hip/hip_runtime.h>

#define OUT_H 256
#define OUT_W 192
#define NPIX  (OUT_H * OUT_W)   // 49152
#define NPP   (NPIX / 2)        // 24576 pixel-pairs
#define NB    256
#define NC    25                 // N_CTRL
#define NL    28                 // NC + 3
#define BCHUNK 16                // batches per block

typedef float f2_t __attribute__((ext_vector_type(2)));
typedef float f4_t __attribute__((ext_vector_type(4)));

// ---------------------------------------------------------------------------
// Compile-time Li = inv(L) (first NC columns), fp64 Gauss-Jordan w/ partial
// pivoting, evaluated by the compiler. cx_log: ln via atanh series (~1e-16).
// ---------------------------------------------------------------------------
constexpr double cx_log(double x) {
    int k = 0;
    while (x > 1.5) { x *= 0.5; ++k; }
    while (x < 0.75) { x *= 2.0; --k; }
    double z = (x - 1.0) / (x + 1.0);
    double z2 = z * z;
    double t = z, s = 0.0;
    for (int i = 0; i < 16; ++i) { s += t / (double)(2 * i + 1); t *= z2; }
    return 2.0 * s + (double)k * 0.69314718055994530941723212145817656808;
}

struct LiMat { float v[NL][NC]; };

constexpr LiMat make_li() {
    double aug[NL][2 * NL] = {};
    const double ax[5] = {-1.0, -0.5, 0.0, 0.5, 1.0};
    for (int i = 0; i < NL; ++i)
        for (int j = 0; j < NL; ++j) {
            double v = 0.0;
            if (i < NC && j < NC) {
                double dx = ax[i / 5] - ax[j / 5];
                double dy = ax[i % 5] - ax[j % 5];
                double d2 = dx * dx + dy * dy;
                v = (d2 == 0.0) ? 0.0 : d2 * cx_log(d2);
            } else if (i < NC) {
                v = (j == NC) ? 1.0 : ((j == NC + 1) ? ax[i / 5] : ax[i % 5]);
            } else if (j < NC) {
                v = (i == NC) ? 1.0 : ((i == NC + 1) ? ax[j / 5] : ax[j % 5]);
            }
            aug[i][j] = (double)(float)v;   // mimic numpy's fp32 L build
        }
    for (int i = 0; i < NL; ++i) aug[i][NL + i] = 1.0;

    for (int k = 0; k < NL; ++k) {
        int p = k;
        double best = aug[k][k] < 0 ? -aug[k][k] : aug[k][k];
        for (int r = k + 1; r < NL; ++r) {
            double a = aug[r][k] < 0 ? -aug[r][k] : aug[r][k];
            if (a > best) { best = a; p = r; }
        }
        if (p != k)
            for (int j = k; j < 2 * NL; ++j) {
                double t = aug[k][j]; aug[k][j] = aug[p][j]; aug[p][j] = t;
            }
        const double ipv = 1.0 / aug[k][k];
        for (int j = k; j < 2 * NL; ++j) aug[k][j] *= ipv;
        for (int r = 0; r < NL; ++r) {
            if (r == k) continue;
            const double f = aug[r][k];
            if (f == 0.0) continue;
            for (int j = k; j < 2 * NL; ++j) aug[r][j] -= f * aug[k][j];
        }
    }
    LiMat o = {};
    for (int i = 0; i < NL; ++i)
        for (int j = 0; j < NC; ++j)
            o.v[i][j] = (float)aug[i][NL + j];
    return o;
}

constexpr LiMat LI_HOST = make_li();
__constant__ LiMat LI = LI_HOST;          // 2.8 KB, baked at compile time

// ---------------------------------------------------------------------------
// Occupancy build: PAIRS=1 (2 px/thread), pk-fma on interleaved (WX,WY)
// pairs, two-chunk c[28] buffer -> ~95-110 VGPR (UNDER the 128 cliff ->
// 4 blocks/CU = 16 waves/CU, 2x R10). NO forced launch_bounds (R12 lesson:
// forcing 5 blocks spilled to scratch, 934 MB FETCH, 10x regression).
// grid (96,16) = 1536 blocks. f4 NT stores (best measured path).
//  swc row layout (stride 56, interleaved):
//    [2n]=WX[n], [2n+1]=WY[n] for n<25;  [50..55] = (A0x,A0y,A1x,A1y,A2x,A2y)
// ---------------------------------------------------------------------------
__global__ __launch_bounds__(256) void tps_fused(const float* __restrict__ theta,
                                                 f4_t* __restrict__ out4) {
    __shared__ float sth[BCHUNK * 2 * NC];   // 800 floats
    __shared__ float swc[BCHUNK][56];        // 16 x 56 coeffs, interleaved

    const int tid = threadIdx.x;
    const int b0  = blockIdx.y * BCHUNK;

    // ---- stage theta slice (coalesced) ----
    #pragma unroll
    for (int k = 0; k < BCHUNK * 2 * NC; k += 256) {
        const int idx = k + tid;
        if (idx < BCHUNK * 2 * NC) sth[idx] = theta[b0 * 2 * NC + idx];
    }
    __syncthreads();

    const float axf[5] = {-1.f, -0.5f, 0.f, 0.5f, 1.f};

    // ---- coefficients: 16 threads/batch, rows 2g and 2g+1 each ----
    {
        const int b = tid >> 4;          // batch 0..15
        const int g = tid & 15;          // row-pair index
        #pragma unroll
        for (int r0 = 0; r0 < 2; ++r0) {
            const int r = g * 2 + r0;
            if (r < NL) {
                float sx = 0.f, sy = 0.f;
                #pragma unroll
                for (int m = 0; m < NC; ++m) {
                    const float l  = LI.v[r][m];
                    const float tx = sth[b * 2 * NC + m]      + axf[m / 5];
                    const float ty = sth[b * 2 * NC + NC + m] + axf[m % 5];
                    sx = fmaf(l, tx, sx);
                    sy = fmaf(l, ty, sy);
                }
                if (r < NC) { swc[b][2 * r] = sx;            swc[b][2 * r + 1] = sy; }
                else        { swc[b][50 + 2 * (r - NC)] = sx; swc[b][51 + 2 * (r - NC)] = sy; }
            }
        }
    }

    // ---- per-thread radial basis for 1 pixel-pair (2 pixels) ----
    const int pp = blockIdx.x * 256 + tid;           // pixel-pair 0..24575
    const int h  = pp / (OUT_W / 2);
    const int w0 = (pp - h * (OUT_W / 2)) * 2;

    const float gy  = (h == OUT_H - 1) ? 1.f : (float)(-1.0 + h * (2.0 / (OUT_H - 1)));
    const float gx0 = (float)(-1.0 + w0 * (2.0 / (OUT_W - 1)));
    const float gx1 = (w0 + 1 == OUT_W - 1) ? 1.f
                                            : (float)(-1.0 + (w0 + 1) * (2.0 / (OUT_W - 1)));

    float U0[NC], U1[NC];
    #pragma unroll
    for (int n = 0; n < NC; ++n) {
        const float cx = axf[n / 5], cy = axf[n % 5];
        const float dy  = gy - cy;
        const float dx0 = gx0 - cx;
        const float d20 = dx0 * dx0 + dy * dy;
        U0[n] = (d20 == 0.f) ? 0.f : d20 * __logf(d20);
        const float dx1 = gx1 - cx;
        const float d21 = dx1 * dx1 + dy * dy;
        U1[n] = (d21 == 0.f) ? 0.f : d21 * __logf(d21);
    }

    __syncthreads();

    // ---- main loop over the block's 16 batches ----
    #pragma unroll 1
    for (int bi = 0; bi < BCHUNK; ++bi) {
        float c[28];                                  // reused two-chunk buffer
        f2_t acc0, acc1;                              // {X0,Y0}, {X1,Y1}

        // chunk A: pairs n = 0..13  (floats 0..27)
        #pragma unroll
        for (int k = 0; k < 7; ++k)
            *(f4_t*)&c[k * 4] = *(const f4_t*)&swc[bi][k * 4];
        {
            const f2_t cp0 = { c[0], c[1] };
            acc0 = cp0; acc1 = cp0;                   // seeded below by A-terms? no:
        }
        // seed accumulators with W-term n=0 product instead of add later:
        {
            f2_t u; u.x = U0[0]; u.y = U0[0];
            f2_t cp; cp.x = c[0]; cp.y = c[1];
            acc0 = u * cp;
            u.x = U1[0]; u.y = U1[0];
            acc1 = u * cp;
        }
        #pragma unroll
        for (int n = 1; n < 14; ++n) {
            f2_t cp; cp.x = c[2 * n]; cp.y = c[2 * n + 1];
            f2_t u0; u0.x = U0[n]; u0.y = U0[n];
            f2_t u1; u1.x = U1[n]; u1.y = U1[n];
            acc0 = __builtin_elementwise_fma(u0, cp, acc0);
            acc1 = __builtin_elementwise_fma(u1, cp, acc1);
        }

        // chunk B: pairs n = 14..24 + A-terms (floats 28..55)
        #pragma unroll
        for (int k = 0; k < 7; ++k)
            *(f4_t*)&c[k * 4] = *(const f4_t*)&swc[bi][28 + k * 4];
        #pragma unroll
        for (int n = 14; n < NC; ++n) {
            f2_t cp; cp.x = c[2 * n - 28]; cp.y = c[2 * n - 27];
            f2_t u0; u0.x = U0[n]; u0.y = U0[n];
            f2_t u1; u1.x = U1[n]; u1.y = U1[n];
            acc0 = __builtin_elementwise_fma(u0, cp, acc0);
            acc1 = __builtin_elementwise_fma(u1, cp, acc1);
        }
        {   // A-terms: c[22..27] = (A0x,A0y,A1x,A1y,A2x,A2y)
            f2_t a0; a0.x = c[22]; a0.y = c[23];
            f2_t a1; a1.x = c[24]; a1.y = c[25];
            f2_t a2; a2.x = c[26]; a2.y = c[27];
            f2_t g0; g0.x = gx0; g0.y = gx0;
            f2_t g1; g1.x = gx1; g1.y = gx1;
            f2_t gyv; gyv.x = gy; gyv.y = gy;
            f2_t p0 = __builtin_elementwise_fma(a2, gyv, __builtin_elementwise_fma(a1, g0, a0));
            f2_t p1 = __builtin_elementwise_fma(a2, gyv, __builtin_elementwise_fma(a1, g1, a0));
            acc0 = acc0 + p0;
            acc1 = acc1 + p1;
        }

        f4_t v; v.x = acc0.x; v.y = acc0.y; v.z = acc1.x; v.w = acc1.y;
        __builtin_nontemporal_store(v, &out4[(size_t)(b0 + bi) * NPP + pp]);
    }
}

// ---------------------------------------------------------------------------
extern "C" void kernel_launch(void* const* d_in, const int* in_sizes, int n_in,
                              void* d_out, int out_size, void* d_ws, size_t ws_size,
                              hipStream_t stream) {
    const float* theta = (const float*)d_in[0];
    dim3 grid(NPP / 256, NB / BCHUNK);             // (96, 16) = 1536 blocks
    tps_fused<<<grid, 256, 0, stream>>>(theta, (f4_t*)d_out);
}

// Round 15
// 34.221 us; speedup vs baseline: 10.8917x; 1.0947x over previous
//
#include <hip/hip_runtime.h>

#define OUT_H 256
#define OUT_W 192
#define NPIX  (OUT_H * OUT_W)   // 49152
#define NPP   (NPIX / 2)        // 24576 pixel-pairs
#define NB    256
#define NC    25                 // N_CTRL
#define NL    28                 // NC + 3
#define BCHUNK 16                // batches per block
#define PAIRS  2                 // pixel-pairs per thread (4 pixels)

typedef float f4_t __attribute__((ext_vector_type(4)));

// ---------------------------------------------------------------------------
// Compile-time Li = inv(L) (first NC columns), fp64 Gauss-Jordan w/ partial
// pivoting, evaluated by the compiler. cx_log: ln via atanh series (~1e-16).
// ---------------------------------------------------------------------------
constexpr double cx_log(double x) {
    int k = 0;
    while (x > 1.5) { x *= 0.5; ++k; }
    while (x < 0.75) { x *= 2.0; --k; }
    double z = (x - 1.0) / (x + 1.0);
    double z2 = z * z;
    double t = z, s = 0.0;
    for (int i = 0; i < 16; ++i) { s += t / (double)(2 * i + 1); t *= z2; }
    return 2.0 * s + (double)k * 0.69314718055994530941723212145817656808;
}

struct LiMat { float v[NL][NC]; };

constexpr LiMat make_li() {
    double aug[NL][2 * NL] = {};
    const double ax[5] = {-1.0, -0.5, 0.0, 0.5, 1.0};
    for (int i = 0; i < NL; ++i)
        for (int j = 0; j < NL; ++j) {
            double v = 0.0;
            if (i < NC && j < NC) {
                double dx = ax[i / 5] - ax[j / 5];
                double dy = ax[i % 5] - ax[j % 5];
                double d2 = dx * dx + dy * dy;
                v = (d2 == 0.0) ? 0.0 : d2 * cx_log(d2);
            } else if (i < NC) {
                v = (j == NC) ? 1.0 : ((j == NC + 1) ? ax[i / 5] : ax[i % 5]);
            } else if (j < NC) {
                v = (i == NC) ? 1.0 : ((i == NC + 1) ? ax[j / 5] : ax[j % 5]);
            }
            aug[i][j] = (double)(float)v;   // mimic numpy's fp32 L build
        }
    for (int i = 0; i < NL; ++i) aug[i][NL + i] = 1.0;

    for (int k = 0; k < NL; ++k) {
        int p = k;
        double best = aug[k][k] < 0 ? -aug[k][k] : aug[k][k];
        for (int r = k + 1; r < NL; ++r) {
            double a = aug[r][k] < 0 ? -aug[r][k] : aug[r][k];
            if (a > best) { best = a; p = r; }
        }
        if (p != k)
            for (int j = k; j < 2 * NL; ++j) {
                double t = aug[k][j]; aug[k][j] = aug[p][j]; aug[p][j] = t;
            }
        const double ipv = 1.0 / aug[k][k];
        for (int j = k; j < 2 * NL; ++j) aug[k][j] *= ipv;
        for (int r = 0; r < NL; ++r) {
            if (r == k) continue;
            const double f = aug[r][k];
            if (f == 0.0) continue;
            for (int j = k; j < 2 * NL; ++j) aug[r][j] -= f * aug[k][j];
        }
    }
    LiMat o = {};
    for (int i = 0; i < NL; ++i)
        for (int j = 0; j < NC; ++j)
            o.v[i][j] = (float)aug[i][NL + j];
    return o;
}

constexpr LiMat LI_HOST = make_li();
__constant__ LiMat LI = LI_HOST;          // 2.8 KB, baked at compile time

// ---------------------------------------------------------------------------
// R10 kernel EXACTLY + one toggle: XCD-chunked bx remap, CORRECTED for
// gridDim.x = 48 (R14 crash: used the [0,96) bijection -> OOB stores).
// bx = (x%8)*6 + x/8 is bijective on [0,48): XCD k gets contiguous bx range
// [6k, 6k+6) -> each XCD writes contiguous 12KB runs per (batch, iter)
// instead of 1KB shards interleaved across all 8 XCDs.
// ---------------------------------------------------------------------------
__global__ __launch_bounds__(256) void tps_fused(const float* __restrict__ theta,
                                                 f4_t* __restrict__ out4) {
    __shared__ float sth[BCHUNK * 2 * NC];   // 800 floats
    __shared__ float swc[BCHUNK][56];        // 16 x 56 coeffs

    const int tid = threadIdx.x;
    const int b0  = blockIdx.y * BCHUNK;
    // XCD-chunked swizzle (single toggle vs R10), bijective on [0,48):
    const int bx  = (blockIdx.x % 8) * 6 + blockIdx.x / 8;

    // ---- stage theta slice (coalesced) ----
    #pragma unroll
    for (int k = 0; k < BCHUNK * 2 * NC; k += 256) {
        const int idx = k + tid;
        if (idx < BCHUNK * 2 * NC) sth[idx] = theta[b0 * 2 * NC + idx];
    }
    __syncthreads();

    const float axf[5] = {-1.f, -0.5f, 0.f, 0.5f, 1.f};

    // ---- coefficient block: b = tid>>4 (16 thr/batch), g = tid&15 rows 2g,2g+1
    {
        const int b = tid >> 4;
        const int g = tid & 15;
        if (g < 14) {
            float qx[NC], qy[NC];
            #pragma unroll
            for (int m = 0; m < NC; ++m) {
                qx[m] = sth[b * 2 * NC + m]      + axf[m / 5];
                qy[m] = sth[b * 2 * NC + NC + m] + axf[m % 5];
            }
            #pragma unroll
            for (int r = 0; r < 2; ++r) {
                const int n = g * 2 + r;
                float sx = 0.f, sy = 0.f;
                #pragma unroll
                for (int m = 0; m < NC; ++m) {
                    const float l = LI.v[n][m];
                    sx = fmaf(l, qx[m], sx);
                    sy = fmaf(l, qy[m], sy);
                }
                if (n < NC) { swc[b][n] = sx;              swc[b][NC + n] = sy; }
                else        { swc[b][50 + (n - NC)] = sx;  swc[b][53 + (n - NC)] = sy; }
            }
        }
    }

    // ---- per-thread radial basis for 2 pixel-pairs (4 pixels) ----
    const int pp0 = bx * (256 * PAIRS) + tid;           // first pair
    float gys[PAIRS], gx0s[PAIRS], gx1s[PAIRS];
    float U[2 * PAIRS][NC];
    #pragma unroll
    for (int q = 0; q < PAIRS; ++q) {
        const int pp = pp0 + q * 256;
        const int h  = pp / (OUT_W / 2);
        const int w0 = (pp - h * (OUT_W / 2)) * 2;
        const float gy  = (h == OUT_H - 1) ? 1.f : (float)(-1.0 + h * (2.0 / (OUT_H - 1)));
        const float gx0 = (float)(-1.0 + w0 * (2.0 / (OUT_W - 1)));
        const float gx1 = (w0 + 1 == OUT_W - 1) ? 1.f
                                                : (float)(-1.0 + (w0 + 1) * (2.0 / (OUT_W - 1)));
        gys[q] = gy; gx0s[q] = gx0; gx1s[q] = gx1;
        #pragma unroll
        for (int n = 0; n < NC; ++n) {
            const float cx = axf[n / 5], cy = axf[n % 5];
            const float dy  = gy - cy;
            const float dx0 = gx0 - cx;
            const float d20 = dx0 * dx0 + dy * dy;
            U[2 * q][n] = (d20 == 0.f) ? 0.f : d20 * __logf(d20);
            const float dx1 = gx1 - cx;
            const float d21 = dx1 * dx1 + dy * dy;
            U[2 * q + 1][n] = (d21 == 0.f) ? 0.f : d21 * __logf(d21);
        }
    }

    __syncthreads();

    // ---- main loop over the block's 16 batches ----
    for (int bi = 0; bi < BCHUNK; ++bi) {
        float c[56];
        #pragma unroll
        for (int k = 0; k < 14; ++k)
            *(f4_t*)&c[k * 4] = *(const f4_t*)&swc[bi][k * 4];   // broadcast b128

        const size_t sbase = (size_t)(b0 + bi) * NPP + pp0;
        #pragma unroll
        for (int q = 0; q < PAIRS; ++q) {
            const float gy = gys[q], gx0 = gx0s[q], gx1 = gx1s[q];
            float X0 = fmaf(c[52], gy, fmaf(c[51], gx0, c[50]));
            float X1 = fmaf(c[52], gy, fmaf(c[51], gx1, c[50]));
            float Y0 = fmaf(c[55], gy, fmaf(c[54], gx0, c[53]));
            float Y1 = fmaf(c[55], gy, fmaf(c[54], gx1, c[53]));
            #pragma unroll
            for (int n = 0; n < NC; ++n) {
                X0 = fmaf(U[2 * q][n],     c[n],      X0);
                X1 = fmaf(U[2 * q + 1][n], c[n],      X1);
                Y0 = fmaf(U[2 * q][n],     c[NC + n], Y0);
                Y1 = fmaf(U[2 * q + 1][n], c[NC + n], Y1);
            }
            f4_t v; v.x = X0; v.y = Y0; v.z = X1; v.w = Y1;
            __builtin_nontemporal_store(v, &out4[sbase + q * 256]);
        }
    }
}

// ---------------------------------------------------------------------------
extern "C" void kernel_launch(void* const* d_in, const int* in_sizes, int n_in,
                              void* d_out, int out_size, void* d_ws, size_t ws_size,
                              hipStream_t stream) {
    const float* theta = (const float*)d_in[0];
    dim3 grid(NPP / (256 * PAIRS), NB / BCHUNK);   // (48, 16) = 768 blocks
    tps_fused<<<grid, 256, 0, stream>>>(theta, (f4_t*)d_out);
}